// Round 12
// baseline (188.173 us; speedup 1.0000x reference)
//
#include <hip/hip_runtime.h>
#include <hip/hip_bf16.h>
#include <math.h>

#define D_MODEL 1024
#define NUM_HEADS 16
#define D_K 64
#define SEQ 1024
#define BATCH 2

typedef __hip_bfloat16 bf16;
typedef __bf16 bf16x8 __attribute__((ext_vector_type(8)));
typedef __bf16 bf16x4 __attribute__((ext_vector_type(4)));
typedef float floatx4 __attribute__((ext_vector_type(4)));

__device__ __forceinline__ floatx4 mfma16(bf16x8 a, bf16x8 b, floatx4 c) {
    return __builtin_amdgcn_mfma_f32_16x16x32_bf16(a, b, c, 0, 0, 0);
}

// Async global->LDS DMA, 16B/lane. LDS dest = wave-uniform base + lane*16.
__device__ __forceinline__ void gl_lds16(const bf16* g, __bf16* l) {
    __builtin_amdgcn_global_load_lds(
        (const __attribute__((address_space(1))) void*)g,
        (__attribute__((address_space(3))) void*)l, 16, 0, 0);
}

// ---------------------------------------------------------------------------
// Dtype probe: flag=1 -> fp32 inputs, 0 -> bf16 (verified in r2-r11).
// ---------------------------------------------------------------------------
__global__ void detect_dtype_kernel(const void* __restrict__ x, int* __restrict__ flag) {
    __shared__ int cnt[256];
    const float* xf = (const float*)x;
    const int tid = threadIdx.x;
    int sane = 0;
    for (int i = tid; i < 4096; i += 256) {
        float v = xf[i];
        float a = fabsf(v);
        if (v == 0.0f || (a > 1e-8f && a < 1e8f)) sane++;
    }
    cnt[tid] = sane;
    __syncthreads();
    for (int s = 128; s > 0; s >>= 1) {
        if (tid < s) cnt[tid] += cnt[tid + s];
        __syncthreads();
    }
    if (tid == 0) flag[0] = (cnt[0] > 3686) ? 1 : 0;
}

// ---------------------------------------------------------------------------
// Fused convert of all 10 inputs into the canonical bf16 region.
// ---------------------------------------------------------------------------
struct ConvSrcs { const void* p[10]; };

__global__ __launch_bounds__(256) void convert_all_kernel(ConvSrcs srcs,
                                                          bf16* __restrict__ dstbase,
                                                          const int* __restrict__ flag) {
    const long long e = ((long long)blockIdx.x * 256 + threadIdx.x) * 8;
    int seg; long long base;
    if      (e < 2097152LL) { seg = 0; base = 0; }
    else if (e < 3145728LL) { seg = 1; base = 2097152LL; }
    else if (e < 4194304LL) { seg = 2; base = 3145728LL; }
    else if (e < 5242880LL) { seg = 3; base = 4194304LL; }
    else if (e < 6291456LL) { seg = 4; base = 5242880LL; }
    else if (e < 6292480LL) { seg = 5; base = 6291456LL; }
    else if (e < 6293504LL) { seg = 6; base = 6292480LL; }
    else if (e < 6294528LL) { seg = 7; base = 6293504LL; }
    else if (e < 6295552LL) { seg = 8; base = 6294528LL; }
    else                    { seg = 9; base = 6295552LL; }
    const long long local = e - base;
    __bf16 tmp[8];
    if (*flag) {
        const float* s = (const float*)srcs.p[seg] + local;
#pragma unroll
        for (int t = 0; t < 8; ++t) tmp[t] = (__bf16)s[t];
        *(bf16x8*)(void*)(dstbase + e) = *(const bf16x8*)tmp;
    } else {
        *(bf16x8*)(void*)(dstbase + e) =
            *(const bf16x8*)(const void*)((const bf16*)srcs.p[seg] + local);
    }
}

// ---------------------------------------------------------------------------
// Fused QKV GEMM, 128x64 tiles (768 blocks -> 3/CU), global_load_lds staging.
// wsel==2 (V) epilogue transposes per-head through smem and writes Vt.
// ---------------------------------------------------------------------------
__global__ __launch_bounds__(256) void gemm_qkv_kernel(const bf16* __restrict__ x,
        const bf16* __restrict__ Wq, const bf16* __restrict__ Wk, const bf16* __restrict__ Wv,
        const bf16* __restrict__ bq, const bf16* __restrict__ bk, const bf16* __restrict__ bv,
        bf16* __restrict__ Qb, bf16* __restrict__ Kb, bf16* __restrict__ Vt) {
    const int wsel = blockIdx.x >> 4;
    const int n0 = (blockIdx.x & 15) * 64;
    const int m0 = blockIdx.y * 128;
    const bf16* W    = (wsel == 0) ? Wq : ((wsel == 1) ? Wk : Wv);
    const bf16* bias = (wsel == 0) ? bq : ((wsel == 1) ? bk : bv);

    __shared__ __bf16 smem[128 * 64 + 64 * 64];  // As | Bs, 24KB
    __bf16* As = smem;
    __bf16* Bs = smem + 8192;

    const int tid = threadIdx.x;
    const int wave = tid >> 6, lane = tid & 63, quad = lane >> 4, l16 = lane & 15;
    const int wr = (wave >> 1) * 64, wc = (wave & 1) * 32;

    floatx4 acc[4][2];
#pragma unroll
    for (int r = 0; r < 4; ++r)
#pragma unroll
        for (int c = 0; c < 2; ++c) acc[r][c] = (floatx4)0.f;

    const int grow = lane >> 3, gcol = (lane & 7) * 8;
    const bf16* xg = x + (size_t)(m0 + grow) * 1024 + gcol;
    const bf16* wg = W + (size_t)(n0 + grow) * 1024 + gcol;

    for (int k0 = 0; k0 < 1024; k0 += 64) {
        __syncthreads();
#pragma unroll
        for (int i = 0; i < 4; ++i) {
            const int ci = wave * 4 + i;
            gl_lds16(xg + (size_t)ci * 8192 + k0, As + ci * 512);
        }
#pragma unroll
        for (int i = 0; i < 2; ++i) {
            const int ci = wave * 2 + i;
            gl_lds16(wg + (size_t)ci * 8192 + k0, Bs + ci * 512);
        }
        __syncthreads();
#pragma unroll
        for (int kk = 0; kk < 2; ++kk) {
            bf16x8 af[4], bfr[2];
#pragma unroll
            for (int r = 0; r < 4; ++r)
                af[r] = *(const bf16x8*)&As[(wr + r * 16 + l16) * 64 + kk * 32 + quad * 8];
#pragma unroll
            for (int c = 0; c < 2; ++c)
                bfr[c] = *(const bf16x8*)&Bs[(wc + c * 16 + l16) * 64 + kk * 32 + quad * 8];
#pragma unroll
            for (int r = 0; r < 4; ++r)
#pragma unroll
                for (int c = 0; c < 2; ++c)
                    acc[r][c] = mfma16(af[r], bfr[c], acc[r][c]);
        }
    }

    if (wsel < 2) {
        bf16* Cb = (wsel == 0) ? Qb : Kb;
#pragma unroll
        for (int c = 0; c < 2; ++c) {
            const int col = n0 + wc + c * 16 + l16;
            const float bvl = (float)bias[col];
#pragma unroll
            for (int r = 0; r < 4; ++r)
#pragma unroll
                for (int v = 0; v < 4; ++v) {
                    const int row = m0 + wr + r * 16 + quad * 4 + v;
                    Cb[(size_t)row * 1024 + col] = (bf16)(acc[r][c][v] + bvl);
                }
        }
    } else {
        __bf16* Ls = smem;   // [64 d][132 stride]
        __syncthreads();
#pragma unroll
        for (int c = 0; c < 2; ++c) {
            const int col = wc + c * 16 + l16;  // d
            const float bvl = (float)bias[n0 + col];
#pragma unroll
            for (int r = 0; r < 4; ++r)
#pragma unroll
                for (int v = 0; v < 4; ++v) {
                    const int row = wr + r * 16 + quad * 4 + v;  // s_local
                    Ls[col * 132 + row] = (__bf16)(acc[r][c][v] + bvl);
                }
        }
        __syncthreads();
        const int b = m0 >> 10, s0 = m0 & 1023, h = n0 >> 6;
        const int d = tid >> 2, sg = (tid & 3) * 32;
        bf16* g = Vt + ((size_t)((b * NUM_HEADS + h) * 64 + d)) * SEQ + s0 + sg;
#pragma unroll
        for (int c = 0; c < 32; c += 8)
            *(bf16x8*)(void*)(g + c) = *(const bf16x8*)&Ls[d * 132 + sg + c];
    }
}

// ---------------------------------------------------------------------------
// Flash attention (r8 structure, 52.9 us) + XCD-AWARE SWIZZLE (r12):
// linear block id -> xcd_v = id&7; each XCD owns 4 (b,h) groups; a group's
// 24 blocks (8 i-tiles x 3 jsel) all satisfy id % 8 == xcd_v, so under the
// round-robin workgroup->XCD dispatch they land on ONE XCD and share its L2
// copy of K/Vt (256 KB per (b,h); 4 groups ~ 1 MB << 4 MB XCD L2). r11
// FETCH=38.6MB vs ~8.5MB working set = cross-XCD replication; staging chain
// is latency-bound, so L2 hits (~200cyc) vs HBM misses (~900cyc) matter.
// Correctness-neutral: pure work relabeling.
// ---------------------------------------------------------------------------
__global__ __launch_bounds__(256, 3) void attn_mfma_kernel(const bf16* __restrict__ Q,
                                                           const bf16* __restrict__ Kc,
                                                           const bf16* __restrict__ Vt,
                                                           const bf16* __restrict__ Er,
                                                           bf16* __restrict__ Opart,
                                                           float* __restrict__ Ml) {
    // ---- XCD swizzle: id in [0,768) -> (i0, h, b, jsel) ----
    const int id = blockIdx.x + 8 * (blockIdx.y + 16 * blockIdx.z);
    const int xcd_v = id & 7;
    const int rem = id >> 3;            // 0..95
    const int u = rem >> 3;             // 0..11 = sub*3 + jsel
    const int ii = rem & 7;             // i-tile index
    const int sub = (u * 11) >> 5;      // u/3 for u in [0,11]
    const int jsel = u - sub * 3;       // u%3
    const int g = xcd_v * 4 + sub;      // (b,h) group 0..31
    const int h = g & 15;
    const int b = g >> 4;
    const int i0 = ii * 128;

    const int tid = threadIdx.x;
    const int wave = tid >> 6, lane = tid & 63, quad = lane >> 4, l16 = lane & 15;

    const int jbeg = (jsel == 0) ? 0 : ((jsel == 1) ? 384 : 704);
    const int nt   = (jsel == 0) ? 6 : 5;

    __shared__ __bf16 Ks[64][72];
    __shared__ __bf16 Vs[80][72];        // rows 0..63: V^T tile; row 64: ones; 65..79: 0
    __shared__ __bf16 scr_all[4][3264];  // per-wave: T' [96][34] / P [32][72]; Qs alias
    __bf16* scr = &scr_all[wave][0];
    __bf16* Qs = &scr_all[0][0];

    for (int e = tid; e < 16 * 72; e += 256) {
        const int r = e / 72, c = e - r * 72;
        Vs[64 + r][c] = (r == 0) ? (__bf16)1.0f : (__bf16)0.0f;
    }
    {   // stage Q (128 rows x 64) into scr alias
        const int r = tid >> 1, cg = (tid & 1) * 32;
        const bf16* gq = Q + ((size_t)(b * SEQ + i0 + r)) * D_MODEL + h * 64 + cg;
#pragma unroll
        for (int c = 0; c < 32; c += 8)
            *(bf16x8*)(void*)(Qs + r * 72 + cg + c) = *(const bf16x8*)(const void*)(gq + c);
    }
    __syncthreads();
    bf16x8 aq[2][2];
#pragma unroll
    for (int half = 0; half < 2; ++half)
#pragma unroll
        for (int kk = 0; kk < 2; ++kk)
            aq[half][kk] = *(const bf16x8*)(const void*)(
                Qs + (wave * 32 + half * 16 + l16) * 72 + kk * 32 + quad * 8);

    floatx4 oacc[5][2];   // ct 0..3: O columns; ct 4: row-sum l
#pragma unroll
    for (int ct = 0; ct < 5; ++ct)
#pragma unroll
        for (int half = 0; half < 2; ++half) oacc[ct][half] = (floatx4)0.f;

    const int eb = 960 + i0;
    const bf16* Kg = Kc + (size_t)b * SEQ * D_MODEL + h * 64;
    const bf16* Vtg = Vt + (size_t)((b * NUM_HEADS + h) * 64) * SEQ;

    const int r4 = tid >> 2, c4 = (tid & 3) * 16;
    bf16x8 kp0, kp1, vp0, vp1;
    {   // prefetch first K/V tile
        const bf16* kg = Kg + (size_t)(jbeg + r4) * D_MODEL + c4;
        const bf16* vg = Vtg + (size_t)r4 * SEQ + jbeg + c4;
        kp0 = *(const bf16x8*)(const void*)kg;
        kp1 = *(const bf16x8*)(const void*)(kg + 8);
        vp0 = *(const bf16x8*)(const void*)vg;
        vp1 = *(const bf16x8*)(const void*)(vg + 8);
    }

    for (int t = 0; t < nt; ++t) {
        const int j0 = jbeg + t * 64;
        __syncthreads();  // barrier A: prior tile's Ks/Vs reads done
        *(bf16x8*)&Ks[r4][c4]     = kp0;
        *(bf16x8*)&Ks[r4][c4 + 8] = kp1;
        *(bf16x8*)&Vs[r4][c4]     = vp0;
        *(bf16x8*)&Vs[r4][c4 + 8] = vp1;
        __syncthreads();  // barrier B: tile visible
        if (t < nt - 1) { // prefetch next tile (overlaps compute below)
            const int jn = j0 + 64;
            const bf16* kg = Kg + (size_t)(jn + r4) * D_MODEL + c4;
            const bf16* vg = Vtg + (size_t)r4 * SEQ + jn + c4;
            kp0 = *(const bf16x8*)(const void*)kg;
            kp1 = *(const bf16x8*)(const void*)(kg + 8);
            vp0 = *(const bf16x8*)(const void*)vg;
            vp1 = *(const bf16x8*)(const void*)(vg + 8);
        }

        // BD: Er b-frags from global, MFMA, spill transposed to wave scratch
#pragma unroll
        for (int ct = 0; ct < 6; ++ct) {
            const int erow = eb - j0 + wave * 32 + ct * 16 + l16;
            const bf16* ep = Er + (size_t)erow * 64 + quad * 8;
            bf16x8 be0 = *(const bf16x8*)(const void*)ep;
            bf16x8 be1 = *(const bf16x8*)(const void*)(ep + 32);
#pragma unroll
            for (int half = 0; half < 2; ++half) {
                floatx4 tv = (floatx4)0.f;
                tv = mfma16(aq[half][0], be0, tv);
                tv = mfma16(aq[half][1], be1, tv);
                bf16x4 tb;
#pragma unroll
                for (int v = 0; v < 4; ++v) tb[v] = (__bf16)tv[v];
                *(bf16x4*)(void*)(scr + (ct * 16 + l16) * 34 + half * 16 + quad * 4) = tb;
            }
        }
        // AC = Q.K^T (hides T'-spill latency)
        floatx4 sfrag[4][2];
#pragma unroll
        for (int ct = 0; ct < 4; ++ct) {
            bf16x8 bk0 = *(const bf16x8*)&Ks[ct * 16 + l16][quad * 8];
            bf16x8 bk1 = *(const bf16x8*)&Ks[ct * 16 + l16][32 + quad * 8];
#pragma unroll
            for (int half = 0; half < 2; ++half) {
                floatx4 s = (floatx4)0.f;
                s = mfma16(aq[half][0], bk0, s);
                s = mfma16(aq[half][1], bk1, s);
                sfrag[ct][half] = s;
            }
        }
        // Phase 1: gather ALL BD values (every T' read completes into sfrag)
#pragma unroll
        for (int ct = 0; ct < 4; ++ct)
#pragma unroll
            for (int half = 0; half < 2; ++half)
#pragma unroll
                for (int v = 0; v < 4; ++v) {
                    const int rl = half * 16 + quad * 4 + v;
                    const int cl = 63 + rl - (ct * 16 + l16);
                    sfrag[ct][half][v] =
                        (sfrag[ct][half][v] + (float)scr[cl * 34 + rl]) * 0.125f;
                }
        // Phase 2: P = exp(score) -> scratch (T' dead; no RAW hazard)
#pragma unroll
        for (int ct = 0; ct < 4; ++ct)
#pragma unroll
            for (int half = 0; half < 2; ++half)
#pragma unroll
                for (int v = 0; v < 4; ++v) {
                    const int rl = half * 16 + quad * 4 + v;
                    scr[rl * 72 + ct * 16 + l16] = (__bf16)__expf(sfrag[ct][half][v]);
                }
        // O += P.V ; l += P.1
        bf16x8 ap[2][2];
#pragma unroll
        for (int half = 0; half < 2; ++half)
#pragma unroll
            for (int kk = 0; kk < 2; ++kk)
                ap[half][kk] = *(const bf16x8*)(const void*)(
                    scr + (half * 16 + l16) * 72 + kk * 32 + quad * 8);
#pragma unroll
        for (int ct = 0; ct < 5; ++ct) {
            bf16x8 bv0 = *(const bf16x8*)&Vs[ct * 16 + l16][quad * 8];
            bf16x8 bv1 = *(const bf16x8*)&Vs[ct * 16 + l16][32 + quad * 8];
#pragma unroll
            for (int half = 0; half < 2; ++half) {
                oacc[ct][half] = mfma16(ap[half][0], bv0, oacc[ct][half]);
                oacc[ct][half] = mfma16(ap[half][1], bv1, oacc[ct][half]);
            }
        }
    }

    // epilogue: unnormalized bf16 O-partials + l
    bf16* Op = Opart + (size_t)jsel * 2097152;
#pragma unroll
    for (int ct = 0; ct < 4; ++ct)
#pragma unroll
        for (int half = 0; half < 2; ++half)
#pragma unroll
            for (int v = 0; v < 4; ++v) {
                const int row = i0 + wave * 32 + half * 16 + quad * 4 + v;
                const int col = h * 64 + ct * 16 + l16;
                Op[((size_t)(b * SEQ + row)) * D_MODEL + col] = (bf16)oacc[ct][half][v];
            }
    if (l16 == 0) {
        const int base = ((jsel * 2 + b) * 16 + h) * 1024;
#pragma unroll
        for (int half = 0; half < 2; ++half)
#pragma unroll
            for (int v = 0; v < 4; ++v) {
                const int ig = i0 + wave * 32 + half * 16 + quad * 4 + v;
                Ml[base + ig] = oacc[4][half][v];
            }
    }
}

// ---------------------------------------------------------------------------
// Combine 3 j-split partials: Ob = (O1~+O2~+O3~) / (l1+l2+l3). 8 elems/thr.
// ---------------------------------------------------------------------------
__global__ __launch_bounds__(256) void combine_kernel(const bf16* __restrict__ Opart,
                                                      const float* __restrict__ Ml,
                                                      bf16* __restrict__ Ob) {
    const int e = (blockIdx.x * 256 + threadIdx.x) * 8;
    const int row = e >> 10;
    const int b = row >> 10, i = row & 1023;
    const int h = (e & 1023) >> 6;
    float l = 0.f;
#pragma unroll
    for (int s = 0; s < 3; ++s) l += Ml[(((s * 2 + b) * 16 + h) << 10) + i];
    const float inv = 1.0f / l;
    bf16x8 o1 = *(const bf16x8*)(const void*)(Opart + e);
    bf16x8 o2 = *(const bf16x8*)(const void*)(Opart + 2097152 + e);
    bf16x8 o3 = *(const bf16x8*)(const void*)(Opart + 4194304 + e);
    bf16x8 o;
#pragma unroll
    for (int v = 0; v < 8; ++v)
        o[v] = (__bf16)(((float)o1[v] + (float)o2[v] + (float)o3[v]) * inv);
    *(bf16x8*)(void*)(Ob + e) = o;
}

// ---------------------------------------------------------------------------
// Output GEMM: 64x64 tiles (512 blocks -> 2/CU), global_load_lds staging,
// dual-dtype store.
// ---------------------------------------------------------------------------
__global__ __launch_bounds__(256) void gemm_out_kernel(const bf16* __restrict__ A,
        const bf16* __restrict__ W, const bf16* __restrict__ bias,
        void* __restrict__ C, const int* __restrict__ flag) {
    const int n0 = blockIdx.x * 64;
    const int m0 = blockIdx.y * 64;
    __shared__ __bf16 smem[64 * 64 * 2];  // As | Bs, 16KB
    __bf16* As = smem;
    __bf16* Bs = smem + 4096;
    const int tid = threadIdx.x;
    const int wave = tid >> 6, lane = tid & 63, quad = lane >> 4, l16 = lane & 15;
    const int wr = (wave >> 1) * 32, wc = (wave & 1) * 32;
    const int grow = lane >> 3, gcol = (lane & 7) * 8;

    floatx4 acc[2][2];
#pragma unroll
    for (int r = 0; r < 2; ++r)
#pragma unroll
        for (int c = 0; c < 2; ++c) acc[r][c] = (floatx4)0.f;

    const bf16* ag = A + (size_t)(m0 + grow) * 1024 + gcol;
    const bf16* bg = W + (size_t)(n0 + grow) * 1024 + gcol;

    for (int k0 = 0; k0 < 1024; k0 += 64) {
        __syncthreads();
#pragma unroll
        for (int i = 0; i < 2; ++i) {
            const int ci = wave * 2 + i;
            gl_lds16(ag + (size_t)ci * 8192 + k0, As + ci * 512);
            gl_lds16(bg + (size_t)ci * 8192 + k0, Bs + ci * 512);
        }
        __syncthreads();
#pragma unroll
        for (int kk = 0; kk < 2; ++kk) {
            bf16x8 af[2], bfr[2];
#pragma unroll
            for (int r = 0; r < 2; ++r)
                af[r] = *(const bf16x8*)&As[(wr + r * 16 + l16) * 64 + kk * 32 + quad * 8];
#pragma unroll
            for (int c = 0; c < 2; ++c)
                bfr[c] = *(const bf16x8*)&Bs[(wc + c * 16 + l16) * 64 + kk * 32 + quad * 8];
#pragma unroll
            for (int r = 0; r < 2; ++r)
#pragma unroll
                for (int c = 0; c < 2; ++c)
                    acc[r][c] = mfma16(af[r], bfr[c], acc[r][c]);
        }
    }
#pragma unroll
    for (int c = 0; c < 2; ++c) {
        const int col = n0 + wc + c * 16 + l16;
        const float bvl = (float)bias[col];
#pragma unroll
        for (int r = 0; r < 2; ++r)
#pragma unroll
            for (int v = 0; v < 4; ++v) {
                const int row = m0 + wr + r * 16 + quad * 4 + v;
                const float val = acc[r][c][v] + bvl;
                const size_t idx = (size_t)row * 1024 + col;
                if (*flag) ((float*)C)[idx] = val;
                else       ((bf16*)C)[idx] = (bf16)val;
            }
    }
}

// ---------------------------------------------------------------------------
extern "C" void kernel_launch(void* const* d_in, const int* in_sizes, int n_in,
                              void* d_out, int out_size, void* d_ws, size_t ws_size,
                              hipStream_t stream) {
    const size_t E_X = 2097152;       // 2048 x 1024
    const size_t E_CANON = 6426624;

    char* ws = (char*)d_ws;
    int* flag = (int*)ws;
    bf16* canon = (bf16*)(ws + 16);
    bf16* xc  = canon;
    bf16* Wqc = canon + 2097152;
    bf16* Wkc = canon + 3145728;
    bf16* Wvc = canon + 4194304;
    bf16* Woc = canon + 5242880;
    bf16* bqc = canon + 6291456;
    bf16* bkc = canon + 6292480;
    bf16* bvc = canon + 6293504;
    bf16* boc = canon + 6294528;
    bf16* Erc = canon + 6295552;
    bf16* p = canon + E_CANON;
    bf16* Qb    = p;  p += E_X;       // reused as Ob after combine
    bf16* Kb    = p;  p += E_X;
    bf16* Vt    = p;  p += E_X;
    bf16* Opart = p;  p += 3 * E_X;   // bf16 unnormalized partials, 3 j-splits
    float* Ml   = (float*)p;          // [3 jsel][2 b][16 h][1024 i] = 98304 f32

    detect_dtype_kernel<<<1, 256, 0, stream>>>(d_in[0], flag);

    ConvSrcs cs;
    cs.p[0] = d_in[0]; cs.p[1] = d_in[1]; cs.p[2] = d_in[3]; cs.p[3] = d_in[5];
    cs.p[4] = d_in[7]; cs.p[5] = d_in[2]; cs.p[6] = d_in[4]; cs.p[7] = d_in[6];
    cs.p[8] = d_in[8]; cs.p[9] = d_in[9];
    convert_all_kernel<<<3138, 256, 0, stream>>>(cs, canon, flag);

    gemm_qkv_kernel<<<dim3(48, 16), 256, 0, stream>>>(xc, Wqc, Wkc, Wvc,
                                                      bqc, bkc, bvc, Qb, Kb, Vt);

    attn_mfma_kernel<<<dim3(8, 16, 6), 256, 0, stream>>>(Qb, Kb, Vt, Erc, Opart, Ml);

    combine_kernel<<<1024, 256, 0, stream>>>(Opart, Ml, Qb);  // Ob overlays Qb

    gemm_out_kernel<<<dim3(16, 32), 256, 0, stream>>>(Qb, Woc, boc, d_out, flag);
}

// Round 13
// 177.837 us; speedup vs baseline: 1.0581x; 1.0581x over previous
//
#include <hip/hip_runtime.h>
#include <hip/hip_bf16.h>
#include <math.h>

#define D_MODEL 1024
#define NUM_HEADS 16
#define D_K 64
#define SEQ 1024
#define BATCH 2

typedef __hip_bfloat16 bf16;
typedef __bf16 bf16x8 __attribute__((ext_vector_type(8)));
typedef __bf16 bf16x4 __attribute__((ext_vector_type(4)));
typedef float floatx4 __attribute__((ext_vector_type(4)));

__device__ __forceinline__ floatx4 mfma16(bf16x8 a, bf16x8 b, floatx4 c) {
    return __builtin_amdgcn_mfma_f32_16x16x32_bf16(a, b, c, 0, 0, 0);
}

// Async global->LDS DMA, 16B/lane. LDS dest = wave-uniform base + lane*16
// (LDS-side constraint only; global side is a normal per-lane gather).
__device__ __forceinline__ void gl_lds16(const bf16* g, __bf16* l) {
    __builtin_amdgcn_global_load_lds(
        (const __attribute__((address_space(1))) void*)g,
        (__attribute__((address_space(3))) void*)l, 16, 0, 0);
}

// ---------------------------------------------------------------------------
// Dtype probe: flag=1 -> fp32 inputs, 0 -> bf16 (verified in r2-r12).
// ---------------------------------------------------------------------------
__global__ void detect_dtype_kernel(const void* __restrict__ x, int* __restrict__ flag) {
    __shared__ int cnt[256];
    const float* xf = (const float*)x;
    const int tid = threadIdx.x;
    int sane = 0;
    for (int i = tid; i < 4096; i += 256) {
        float v = xf[i];
        float a = fabsf(v);
        if (v == 0.0f || (a > 1e-8f && a < 1e8f)) sane++;
    }
    cnt[tid] = sane;
    __syncthreads();
    for (int s = 128; s > 0; s >>= 1) {
        if (tid < s) cnt[tid] += cnt[tid + s];
        __syncthreads();
    }
    if (tid == 0) flag[0] = (cnt[0] > 3686) ? 1 : 0;
}

// ---------------------------------------------------------------------------
// Fused convert of all 10 inputs into the canonical bf16 region.
// ---------------------------------------------------------------------------
struct ConvSrcs { const void* p[10]; };

__global__ __launch_bounds__(256) void convert_all_kernel(ConvSrcs srcs,
                                                          bf16* __restrict__ dstbase,
                                                          const int* __restrict__ flag) {
    const long long e = ((long long)blockIdx.x * 256 + threadIdx.x) * 8;
    int seg; long long base;
    if      (e < 2097152LL) { seg = 0; base = 0; }
    else if (e < 3145728LL) { seg = 1; base = 2097152LL; }
    else if (e < 4194304LL) { seg = 2; base = 3145728LL; }
    else if (e < 5242880LL) { seg = 3; base = 4194304LL; }
    else if (e < 6291456LL) { seg = 4; base = 5242880LL; }
    else if (e < 6292480LL) { seg = 5; base = 6291456LL; }
    else if (e < 6293504LL) { seg = 6; base = 6292480LL; }
    else if (e < 6294528LL) { seg = 7; base = 6293504LL; }
    else if (e < 6295552LL) { seg = 8; base = 6294528LL; }
    else                    { seg = 9; base = 6295552LL; }
    const long long local = e - base;
    __bf16 tmp[8];
    if (*flag) {
        const float* s = (const float*)srcs.p[seg] + local;
#pragma unroll
        for (int t = 0; t < 8; ++t) tmp[t] = (__bf16)s[t];
        *(bf16x8*)(void*)(dstbase + e) = *(const bf16x8*)tmp;
    } else {
        *(bf16x8*)(void*)(dstbase + e) =
            *(const bf16x8*)(const void*)((const bf16*)srcs.p[seg] + local);
    }
}

// ---------------------------------------------------------------------------
// Fused QKV GEMM (r13): 128x64 tiles, BK=128 (8 k-iters -> half the barriers,
// 32 MFMA per barrier-pair), XOR-swizzled global_load_lds staging:
// lane fetches global col-group (l&15)^(row&15), so stored slot s holds
// global group s^(row&15); readers use slot (g^(row&15)) -> b-frag reads
// land 2-way per bank (free, m136) instead of 16-way (5.69x, unpadded).
// LDS 48KB -> 3 blocks/CU; 768 blocks = 3/CU tail-free.
// wsel==2 (V) epilogue transposes per-head through smem and writes Vt.
// ---------------------------------------------------------------------------
__global__ __launch_bounds__(256) void gemm_qkv_kernel(const bf16* __restrict__ x,
        const bf16* __restrict__ Wq, const bf16* __restrict__ Wk, const bf16* __restrict__ Wv,
        const bf16* __restrict__ bq, const bf16* __restrict__ bk, const bf16* __restrict__ bv,
        bf16* __restrict__ Qb, bf16* __restrict__ Kb, bf16* __restrict__ Vt) {
    const int wsel = blockIdx.x >> 4;
    const int n0 = (blockIdx.x & 15) * 64;
    const int m0 = blockIdx.y * 128;
    const bf16* W    = (wsel == 0) ? Wq : ((wsel == 1) ? Wk : Wv);
    const bf16* bias = (wsel == 0) ? bq : ((wsel == 1) ? bk : bv);

    __shared__ __bf16 smem[128 * 128 + 64 * 128];  // As | Bs, 48KB
    __bf16* As = smem;           // [128][128]
    __bf16* Bs = smem + 16384;   // [64][128]

    const int tid = threadIdx.x;
    const int wave = tid >> 6, lane = tid & 63, quad = lane >> 4, l16 = lane & 15;
    const int wr = (wave >> 1) * 64, wc = (wave & 1) * 32;
    const int lrow = lane >> 4;      // row within 4-row DMA chunk
    const int lcg  = lane & 15;      // stored col-group (8 elems)

    floatx4 acc[4][2];
#pragma unroll
    for (int r = 0; r < 4; ++r)
#pragma unroll
        for (int c = 0; c < 2; ++c) acc[r][c] = (floatx4)0.f;

    for (int k0 = 0; k0 < 1024; k0 += 128) {
        __syncthreads();   // prior-iter MFMA LDS reads done
#pragma unroll
        for (int i = 0; i < 8; ++i) {
            const int ci = wave * 8 + i;                 // As chunk 0..31
            const int grow = ci * 4 + lrow;              // 0..127
            const int gcg = lcg ^ (grow & 15);
            gl_lds16(x + (size_t)(m0 + grow) * 1024 + k0 + gcg * 8, As + ci * 512);
        }
#pragma unroll
        for (int i = 0; i < 4; ++i) {
            const int ci = wave * 4 + i;                 // Bs chunk 0..15
            const int grow = ci * 4 + lrow;              // 0..63
            const int gcg = lcg ^ (grow & 15);
            gl_lds16(W + (size_t)(n0 + grow) * 1024 + k0 + gcg * 8, Bs + ci * 512);
        }
        __syncthreads();   // vmcnt drain -> tile visible
#pragma unroll
        for (int kk = 0; kk < 4; ++kk) {
            bf16x8 af[4], bfr[2];
#pragma unroll
            for (int r = 0; r < 4; ++r) {
                const int row = wr + r * 16 + l16;
                const int sg = (kk * 4 + quad) ^ l16;    // row&15 == l16
                af[r] = *(const bf16x8*)&As[row * 128 + sg * 8];
            }
#pragma unroll
            for (int c = 0; c < 2; ++c) {
                const int row = wc + c * 16 + l16;
                const int sg = (kk * 4 + quad) ^ l16;
                bfr[c] = *(const bf16x8*)&Bs[row * 128 + sg * 8];
            }
#pragma unroll
            for (int r = 0; r < 4; ++r)
#pragma unroll
                for (int c = 0; c < 2; ++c)
                    acc[r][c] = mfma16(af[r], bfr[c], acc[r][c]);
        }
    }

    if (wsel < 2) {
        bf16* Cb = (wsel == 0) ? Qb : Kb;
#pragma unroll
        for (int c = 0; c < 2; ++c) {
            const int col = n0 + wc + c * 16 + l16;
            const float bvl = (float)bias[col];
#pragma unroll
            for (int r = 0; r < 4; ++r)
#pragma unroll
                for (int v = 0; v < 4; ++v) {
                    const int row = m0 + wr + r * 16 + quad * 4 + v;
                    Cb[(size_t)row * 1024 + col] = (bf16)(acc[r][c][v] + bvl);
                }
        }
    } else {
        __bf16* Ls = smem;   // [64 d][132 stride] = 16.9KB scratch
        __syncthreads();     // all MFMA LDS reads done before overwrite
#pragma unroll
        for (int c = 0; c < 2; ++c) {
            const int col = wc + c * 16 + l16;  // d
            const float bvl = (float)bias[n0 + col];
#pragma unroll
            for (int r = 0; r < 4; ++r)
#pragma unroll
                for (int v = 0; v < 4; ++v) {
                    const int row = wr + r * 16 + quad * 4 + v;  // s_local
                    Ls[col * 132 + row] = (__bf16)(acc[r][c][v] + bvl);
                }
        }
        __syncthreads();
        const int b = m0 >> 10, s0 = m0 & 1023, h = n0 >> 6;
        const int d = tid >> 2, sg2 = (tid & 3) * 32;
        bf16* g = Vt + ((size_t)((b * NUM_HEADS + h) * 64 + d)) * SEQ + s0 + sg2;
#pragma unroll
        for (int c = 0; c < 32; c += 8)
            *(bf16x8*)(void*)(g + c) = *(const bf16x8*)&Ls[d * 132 + sg2 + c];
    }
}

// ---------------------------------------------------------------------------
// Flash attention (r8/r11 structure — best measured 52.9 us; r12 XCD swizzle
// reverted: FETCH dropped 3.6x but dur rose 2.2 us -> HBM not on the critical
// path; attn is pinned by the barrier-convoy + LDS round-trip chain).
// ---------------------------------------------------------------------------
__global__ __launch_bounds__(256, 3) void attn_mfma_kernel(const bf16* __restrict__ Q,
                                                           const bf16* __restrict__ Kc,
                                                           const bf16* __restrict__ Vt,
                                                           const bf16* __restrict__ Er,
                                                           bf16* __restrict__ Opart,
                                                           float* __restrict__ Ml) {
    const int i0 = blockIdx.x * 128;
    const int h = blockIdx.y;
    const int zz = blockIdx.z;
    const int b = zz / 3, jsel = zz - b * 3;
    const int tid = threadIdx.x;
    const int wave = tid >> 6, lane = tid & 63, quad = lane >> 4, l16 = lane & 15;

    const int jbeg = (jsel == 0) ? 0 : ((jsel == 1) ? 384 : 704);
    const int nt   = (jsel == 0) ? 6 : 5;

    __shared__ __bf16 Ks[64][72];
    __shared__ __bf16 Vs[80][72];        // rows 0..63: V^T tile; row 64: ones; 65..79: 0
    __shared__ __bf16 scr_all[4][3264];  // per-wave: T' [96][34] / P [32][72]; Qs alias
    __bf16* scr = &scr_all[wave][0];
    __bf16* Qs = &scr_all[0][0];

    for (int e = tid; e < 16 * 72; e += 256) {
        const int r = e / 72, c = e - r * 72;
        Vs[64 + r][c] = (r == 0) ? (__bf16)1.0f : (__bf16)0.0f;
    }
    {   // stage Q (128 rows x 64) into scr alias
        const int r = tid >> 1, cg = (tid & 1) * 32;
        const bf16* g = Q + ((size_t)(b * SEQ + i0 + r)) * D_MODEL + h * 64 + cg;
#pragma unroll
        for (int c = 0; c < 32; c += 8)
            *(bf16x8*)(void*)(Qs + r * 72 + cg + c) = *(const bf16x8*)(const void*)(g + c);
    }
    __syncthreads();
    bf16x8 aq[2][2];
#pragma unroll
    for (int half = 0; half < 2; ++half)
#pragma unroll
        for (int kk = 0; kk < 2; ++kk)
            aq[half][kk] = *(const bf16x8*)(const void*)(
                Qs + (wave * 32 + half * 16 + l16) * 72 + kk * 32 + quad * 8);

    floatx4 oacc[5][2];   // ct 0..3: O columns; ct 4: row-sum l
#pragma unroll
    for (int ct = 0; ct < 5; ++ct)
#pragma unroll
        for (int half = 0; half < 2; ++half) oacc[ct][half] = (floatx4)0.f;

    const int eb = 960 + i0;
    const bf16* Kg = Kc + (size_t)b * SEQ * D_MODEL + h * 64;
    const bf16* Vtg = Vt + (size_t)((b * NUM_HEADS + h) * 64) * SEQ;

    const int r4 = tid >> 2, c4 = (tid & 3) * 16;
    bf16x8 kp0, kp1, vp0, vp1;
    {   // prefetch first K/V tile
        const bf16* kg = Kg + (size_t)(jbeg + r4) * D_MODEL + c4;
        const bf16* vg = Vtg + (size_t)r4 * SEQ + jbeg + c4;
        kp0 = *(const bf16x8*)(const void*)kg;
        kp1 = *(const bf16x8*)(const void*)(kg + 8);
        vp0 = *(const bf16x8*)(const void*)vg;
        vp1 = *(const bf16x8*)(const void*)(vg + 8);
    }

    for (int t = 0; t < nt; ++t) {
        const int j0 = jbeg + t * 64;
        __syncthreads();  // barrier A: prior tile's Ks/Vs reads done
        *(bf16x8*)&Ks[r4][c4]     = kp0;
        *(bf16x8*)&Ks[r4][c4 + 8] = kp1;
        *(bf16x8*)&Vs[r4][c4]     = vp0;
        *(bf16x8*)&Vs[r4][c4 + 8] = vp1;
        __syncthreads();  // barrier B: tile visible
        if (t < nt - 1) { // prefetch next tile (overlaps compute below)
            const int jn = j0 + 64;
            const bf16* kg = Kg + (size_t)(jn + r4) * D_MODEL + c4;
            const bf16* vg = Vtg + (size_t)r4 * SEQ + jn + c4;
            kp0 = *(const bf16x8*)(const void*)kg;
            kp1 = *(const bf16x8*)(const void*)(kg + 8);
            vp0 = *(const bf16x8*)(const void*)vg;
            vp1 = *(const bf16x8*)(const void*)(vg + 8);
        }

        // BD: Er b-frags from global, MFMA, spill transposed to wave scratch
#pragma unroll
        for (int ct = 0; ct < 6; ++ct) {
            const int erow = eb - j0 + wave * 32 + ct * 16 + l16;
            const bf16* ep = Er + (size_t)erow * 64 + quad * 8;
            bf16x8 be0 = *(const bf16x8*)(const void*)ep;
            bf16x8 be1 = *(const bf16x8*)(const void*)(ep + 32);
#pragma unroll
            for (int half = 0; half < 2; ++half) {
                floatx4 tv = (floatx4)0.f;
                tv = mfma16(aq[half][0], be0, tv);
                tv = mfma16(aq[half][1], be1, tv);
                bf16x4 tb;
#pragma unroll
                for (int v = 0; v < 4; ++v) tb[v] = (__bf16)tv[v];
                *(bf16x4*)(void*)(scr + (ct * 16 + l16) * 34 + half * 16 + quad * 4) = tb;
            }
        }
        // AC = Q.K^T (hides T'-spill latency)
        floatx4 sfrag[4][2];
#pragma unroll
        for (int ct = 0; ct < 4; ++ct) {
            bf16x8 bk0 = *(const bf16x8*)&Ks[ct * 16 + l16][quad * 8];
            bf16x8 bk1 = *(const bf16x8*)&Ks[ct * 16 + l16][32 + quad * 8];
#pragma unroll
            for (int half = 0; half < 2; ++half) {
                floatx4 s = (floatx4)0.f;
                s = mfma16(aq[half][0], bk0, s);
                s = mfma16(aq[half][1], bk1, s);
                sfrag[ct][half] = s;
            }
        }
        // Phase 1: gather ALL BD values (every T' read completes into sfrag)
#pragma unroll
        for (int ct = 0; ct < 4; ++ct)
#pragma unroll
            for (int half = 0; half < 2; ++half)
#pragma unroll
                for (int v = 0; v < 4; ++v) {
                    const int rl = half * 16 + quad * 4 + v;
                    const int cl = 63 + rl - (ct * 16 + l16);
                    sfrag[ct][half][v] =
                        (sfrag[ct][half][v] + (float)scr[cl * 34 + rl]) * 0.125f;
                }
        // Phase 2: P = exp(score) -> scratch (T' dead; no RAW hazard)
#pragma unroll
        for (int ct = 0; ct < 4; ++ct)
#pragma unroll
            for (int half = 0; half < 2; ++half)
#pragma unroll
                for (int v = 0; v < 4; ++v) {
                    const int rl = half * 16 + quad * 4 + v;
                    scr[rl * 72 + ct * 16 + l16] = (__bf16)__expf(sfrag[ct][half][v]);
                }
        // O += P.V ; l += P.1
        bf16x8 ap[2][2];
#pragma unroll
        for (int half = 0; half < 2; ++half)
#pragma unroll
            for (int kk = 0; kk < 2; ++kk)
                ap[half][kk] = *(const bf16x8*)(const void*)(
                    scr + (half * 16 + l16) * 72 + kk * 32 + quad * 8);
#pragma unroll
        for (int ct = 0; ct < 5; ++ct) {
            bf16x8 bv0 = *(const bf16x8*)&Vs[ct * 16 + l16][quad * 8];
            bf16x8 bv1 = *(const bf16x8*)&Vs[ct * 16 + l16][32 + quad * 8];
#pragma unroll
            for (int half = 0; half < 2; ++half) {
                oacc[ct][half] = mfma16(ap[half][0], bv0, oacc[ct][half]);
                oacc[ct][half] = mfma16(ap[half][1], bv1, oacc[ct][half]);
            }
        }
    }

    // epilogue: unnormalized bf16 O-partials + l
    bf16* Op = Opart + (size_t)jsel * 2097152;
#pragma unroll
    for (int ct = 0; ct < 4; ++ct)
#pragma unroll
        for (int half = 0; half < 2; ++half)
#pragma unroll
            for (int v = 0; v < 4; ++v) {
                const int row = i0 + wave * 32 + half * 16 + quad * 4 + v;
                const int col = h * 64 + ct * 16 + l16;
                Op[((size_t)(b * SEQ + row)) * D_MODEL + col] = (bf16)oacc[ct][half][v];
            }
    if (l16 == 0) {
        const int base = ((jsel * 2 + b) * 16 + h) * 1024;
#pragma unroll
        for (int half = 0; half < 2; ++half)
#pragma unroll
            for (int v = 0; v < 4; ++v) {
                const int ig = i0 + wave * 32 + half * 16 + quad * 4 + v;
                Ml[base + ig] = oacc[4][half][v];
            }
    }
}

// ---------------------------------------------------------------------------
// Combine 3 j-split partials: Ob = (O1~+O2~+O3~) / (l1+l2+l3). 8 elems/thr.
// ---------------------------------------------------------------------------
__global__ __launch_bounds__(256) void combine_kernel(const bf16* __restrict__ Opart,
                                                      const float* __restrict__ Ml,
                                                      bf16* __restrict__ Ob) {
    const int e = (blockIdx.x * 256 + threadIdx.x) * 8;
    const int row = e >> 10;
    const int b = row >> 10, i = row & 1023;
    const int h = (e & 1023) >> 6;
    float l = 0.f;
#pragma unroll
    for (int s = 0; s < 3; ++s) l += Ml[(((s * 2 + b) * 16 + h) << 10) + i];
    const float inv = 1.0f / l;
    bf16x8 o1 = *(const bf16x8*)(const void*)(Opart + e);
    bf16x8 o2 = *(const bf16x8*)(const void*)(Opart + 2097152 + e);
    bf16x8 o3 = *(const bf16x8*)(const void*)(Opart + 4194304 + e);
    bf16x8 o;
#pragma unroll
    for (int v = 0; v < 8; ++v)
        o[v] = (__bf16)(((float)o1[v] + (float)o2[v] + (float)o3[v]) * inv);
    *(bf16x8*)(void*)(Ob + e) = o;
}

// ---------------------------------------------------------------------------
// Output GEMM (r13): 64x64 tiles, BK=128, XOR-swizzled DMA staging (same
// scheme as qkv). LDS 32KB; 512 blocks -> 2/CU. Dual-dtype store.
// ---------------------------------------------------------------------------
__global__ __launch_bounds__(256) void gemm_out_kernel(const bf16* __restrict__ A,
        const bf16* __restrict__ W, const bf16* __restrict__ bias,
        void* __restrict__ C, const int* __restrict__ flag) {
    const int n0 = blockIdx.x * 64;
    const int m0 = blockIdx.y * 64;
    __shared__ __bf16 smem[64 * 128 * 2];  // As | Bs, 32KB
    __bf16* As = smem;          // [64][128]
    __bf16* Bs = smem + 8192;   // [64][128]
    const int tid = threadIdx.x;
    const int wave = tid >> 6, lane = tid & 63, quad = lane >> 4, l16 = lane & 15;
    const int wr = (wave >> 1) * 32, wc = (wave & 1) * 32;
    const int lrow = lane >> 4, lcg = lane & 15;

    floatx4 acc[2][2];
#pragma unroll
    for (int r = 0; r < 2; ++r)
#pragma unroll
        for (int c = 0; c < 2; ++c) acc[r][c] = (floatx4)0.f;

    for (int k0 = 0; k0 < 1024; k0 += 128) {
        __syncthreads();
#pragma unroll
        for (int i = 0; i < 4; ++i) {
            const int ci = wave * 4 + i;                 // chunks 0..15
            const int grow = ci * 4 + lrow;              // 0..63
            const int gcg = lcg ^ (grow & 15);
            gl_lds16(A + (size_t)(m0 + grow) * 1024 + k0 + gcg * 8, As + ci * 512);
            gl_lds16(W + (size_t)(n0 + grow) * 1024 + k0 + gcg * 8, Bs + ci * 512);
        }
        __syncthreads();
#pragma unroll
        for (int kk = 0; kk < 4; ++kk) {
            bf16x8 af[2], bfr[2];
            const int sg = (kk * 4 + quad) ^ l16;
#pragma unroll
            for (int r = 0; r < 2; ++r)
                af[r] = *(const bf16x8*)&As[(wr + r * 16 + l16) * 128 + sg * 8];
#pragma unroll
            for (int c = 0; c < 2; ++c)
                bfr[c] = *(const bf16x8*)&Bs[(wc + c * 16 + l16) * 128 + sg * 8];
#pragma unroll
            for (int r = 0; r < 2; ++r)
#pragma unroll
                for (int c = 0; c < 2; ++c)
                    acc[r][c] = mfma16(af[r], bfr[c], acc[r][c]);
        }
    }
#pragma unroll
    for (int c = 0; c < 2; ++c) {
        const int col = n0 + wc + c * 16 + l16;
        const float bvl = (float)bias[col];
#pragma unroll
        for (int r = 0; r < 2; ++r)
#pragma unroll
            for (int v = 0; v < 4; ++v) {
                const int row = m0 + wr + r * 16 + quad * 4 + v;
                const float val = acc[r][c][v] + bvl;
                const size_t idx = (size_t)row * 1024 + col;
                if (*flag) ((float*)C)[idx] = val;
                else       ((bf16*)C)[idx] = (bf16)val;
            }
    }
}

// ---------------------------------------------------------------------------
extern "C" void kernel_launch(void* const* d_in, const int* in_sizes, int n_in,
                              void* d_out, int out_size, void* d_ws, size_t ws_size,
                              hipStream_t stream) {
    const size_t E_X = 2097152;       // 2048 x 1024
    const size_t E_CANON = 6426624;

    char* ws = (char*)d_ws;
    int* flag = (int*)ws;
    bf16* canon = (bf16*)(ws + 16);
    bf16* xc  = canon;
    bf16* Wqc = canon + 2097152;
    bf16* Wkc = canon + 3145728;
    bf16* Wvc = canon + 4194304;
    bf16* Woc = canon + 5242880;
    bf16* bqc = canon + 6291456;
    bf16* bkc = canon + 6292480;
    bf16* bvc = canon + 6293504;
    bf16* boc = canon + 6294528;
    bf16* Erc = canon + 6295552;
    bf16* p = canon + E_CANON;
    bf16* Qb    = p;  p += E_X;       // reused as Ob after combine
    bf16* Kb    = p;  p += E_X;
    bf16* Vt    = p;  p += E_X;
    bf16* Opart = p;  p += 3 * E_X;   // bf16 unnormalized partials, 3 j-splits
    float* Ml   = (float*)p;          // [3 jsel][2 b][16 h][1024 i] = 98304 f32

    detect_dtype_kernel<<<1, 256, 0, stream>>>(d_in[0], flag);

    ConvSrcs cs;
    cs.p[0] = d_in[0]; cs.p[1] = d_in[1]; cs.p[2] = d_in[3]; cs.p[3] = d_in[5];
    cs.p[4] = d_in[7]; cs.p[5] = d_in[2]; cs.p[6] = d_in[4]; cs.p[7] = d_in[6];
    cs.p[8] = d_in[8]; cs.p[9] = d_in[9];
    convert_all_kernel<<<3138, 256, 0, stream>>>(cs, canon, flag);

    gemm_qkv_kernel<<<dim3(48, 16), 256, 0, stream>>>(xc, Wqc, Wkc, Wvc,
                                                      bqc, bkc, bvc, Qb, Kb, Vt);

    attn_mfma_kernel<<<dim3(8, 16, 6), 256, 0, stream>>>(Qb, Kb, Vt, Erc, Opart, Ml);

    combine_kernel<<<1024, 256, 0, stream>>>(Opart, Ml, Qb);  // Ob overlays Qb

    gemm_out_kernel<<<dim3(16, 32), 256, 0, stream>>>(Qb, Woc, boc, d_out, flag);
}

// Round 14
// 177.080 us; speedup vs baseline: 1.0626x; 1.0043x over previous
//
#include <hip/hip_runtime.h>
#include <hip/hip_bf16.h>
#include <math.h>

#define D_MODEL 1024
#define NUM_HEADS 16
#define D_K 64
#define SEQ 1024
#define BATCH 2

typedef __hip_bfloat16 bf16;
typedef __bf16 bf16x8 __attribute__((ext_vector_type(8)));
typedef __bf16 bf16x4 __attribute__((ext_vector_type(4)));
typedef float floatx4 __attribute__((ext_vector_type(4)));

__device__ __forceinline__ floatx4 mfma16(bf16x8 a, bf16x8 b, floatx4 c) {
    return __builtin_amdgcn_mfma_f32_16x16x32_bf16(a, b, c, 0, 0, 0);
}

// Async global->LDS DMA, 16B/lane. LDS dest = wave-uniform base + lane*16.
__device__ __forceinline__ void gl_lds16(const bf16* g, __bf16* l) {
    __builtin_amdgcn_global_load_lds(
        (const __attribute__((address_space(1))) void*)g,
        (__attribute__((address_space(3))) void*)l, 16, 0, 0);
}

// ---------------------------------------------------------------------------
// Fused convert + SELF-PROBING dtype detect (r14: detect kernel removed).
// Each block reads x's first 4KB as fp32 (L2-hot, identical data -> identical
// verdict): fp32 N(0,1) ~100% sane; bf16-reinterp ~0%. Block 0 publishes the
// flag for gemm_out's dual-dtype store.
// ---------------------------------------------------------------------------
struct ConvSrcs { const void* p[10]; };

__global__ __launch_bounds__(256) void convert_all_kernel(ConvSrcs srcs,
                                                          bf16* __restrict__ dstbase,
                                                          int* __restrict__ flagg) {
    __shared__ int cnt[256];
    const int tid = threadIdx.x;
    {   // per-block dtype probe over x[0:1024] fp32 words
        const float* xf = (const float*)srcs.p[0];
        int sane = 0;
#pragma unroll
        for (int i = 0; i < 4; ++i) {
            const float v = xf[tid * 4 + i];
            const float a = fabsf(v);
            if (v == 0.0f || (a > 1e-8f && a < 1e8f)) sane++;
        }
        cnt[tid] = sane;
    }
    __syncthreads();
    for (int s = 128; s > 0; s >>= 1) {
        if (tid < s) cnt[tid] += cnt[tid + s];
        __syncthreads();
    }
    const int flag = (cnt[0] > 922) ? 1 : 0;   // >90% of 1024 sane -> fp32
    if (blockIdx.x == 0 && tid == 0) flagg[0] = flag;

    const long long e = ((long long)blockIdx.x * 256 + tid) * 8;
    int seg; long long base;
    if      (e < 2097152LL) { seg = 0; base = 0; }
    else if (e < 3145728LL) { seg = 1; base = 2097152LL; }
    else if (e < 4194304LL) { seg = 2; base = 3145728LL; }
    else if (e < 5242880LL) { seg = 3; base = 4194304LL; }
    else if (e < 6291456LL) { seg = 4; base = 5242880LL; }
    else if (e < 6292480LL) { seg = 5; base = 6291456LL; }
    else if (e < 6293504LL) { seg = 6; base = 6292480LL; }
    else if (e < 6294528LL) { seg = 7; base = 6293504LL; }
    else if (e < 6295552LL) { seg = 8; base = 6294528LL; }
    else                    { seg = 9; base = 6295552LL; }
    const long long local = e - base;
    __bf16 tmp[8];
    if (flag) {
        const float* s = (const float*)srcs.p[seg] + local;
#pragma unroll
        for (int t = 0; t < 8; ++t) tmp[t] = (__bf16)s[t];
        *(bf16x8*)(void*)(dstbase + e) = *(const bf16x8*)tmp;
    } else {
        *(bf16x8*)(void*)(dstbase + e) =
            *(const bf16x8*)(const void*)((const bf16*)srcs.p[seg] + local);
    }
}

// ---------------------------------------------------------------------------
// Fused QKV GEMM (r14): 128x128 tiles, BK=128, XOR-swizzled DMA staging.
// 4 waves in 2x2 of 64x64 (4x4 frags): 8 LDS reads feed 16 MFMAs per kk
// (vs 6 reads/8 MFMAs at 64-wide N; m105/m112: 128^2 tile ~1.7-2.6x better).
// LDS 64KB -> 2 blocks/CU; grid 24x16 = 384 blocks (all co-resident).
// wsel==2 (V): epilogue transposes TWO heads per block through smem -> Vt.
// ---------------------------------------------------------------------------
__global__ __launch_bounds__(256, 2) void gemm_qkv_kernel(const bf16* __restrict__ x,
        const bf16* __restrict__ Wq, const bf16* __restrict__ Wk, const bf16* __restrict__ Wv,
        const bf16* __restrict__ bq, const bf16* __restrict__ bk, const bf16* __restrict__ bv,
        bf16* __restrict__ Qb, bf16* __restrict__ Kb, bf16* __restrict__ Vt) {
    const int wsel = blockIdx.x >> 3;
    const int n0 = (blockIdx.x & 7) * 128;
    const int m0 = blockIdx.y * 128;
    const bf16* W    = (wsel == 0) ? Wq : ((wsel == 1) ? Wk : Wv);
    const bf16* bias = (wsel == 0) ? bq : ((wsel == 1) ? bk : bv);

    __shared__ __bf16 smem[128 * 128 * 2];  // As | Bs, 64KB
    __bf16* As = smem;           // [128][128]
    __bf16* Bs = smem + 16384;   // [128][128]

    const int tid = threadIdx.x;
    const int wave = tid >> 6, lane = tid & 63, quad = lane >> 4, l16 = lane & 15;
    const int wr = (wave >> 1) * 64, wc = (wave & 1) * 64;
    const int lrow = lane >> 4;      // row within 4-row DMA chunk
    const int lcg  = lane & 15;      // stored col-group

    floatx4 acc[4][4];
#pragma unroll
    for (int r = 0; r < 4; ++r)
#pragma unroll
        for (int c = 0; c < 4; ++c) acc[r][c] = (floatx4)0.f;

    for (int k0 = 0; k0 < 1024; k0 += 128) {
        __syncthreads();   // prior-iter MFMA LDS reads done
#pragma unroll
        for (int i = 0; i < 8; ++i) {
            const int ci = wave * 8 + i;                 // chunks 0..31
            const int grow = ci * 4 + lrow;              // 0..127
            const int gcg = lcg ^ (grow & 15);
            gl_lds16(x + (size_t)(m0 + grow) * 1024 + k0 + gcg * 8, As + ci * 512);
            gl_lds16(W + (size_t)(n0 + grow) * 1024 + k0 + gcg * 8, Bs + ci * 512);
        }
        __syncthreads();   // vmcnt drain -> tile visible
#pragma unroll
        for (int kk = 0; kk < 4; ++kk) {
            const int sg = ((kk * 4 + quad) ^ l16) * 8;  // row&15 == l16
            bf16x8 af[4], bfr[4];
#pragma unroll
            for (int r = 0; r < 4; ++r)
                af[r] = *(const bf16x8*)&As[(wr + r * 16 + l16) * 128 + sg];
#pragma unroll
            for (int c = 0; c < 4; ++c)
                bfr[c] = *(const bf16x8*)&Bs[(wc + c * 16 + l16) * 128 + sg];
#pragma unroll
            for (int r = 0; r < 4; ++r)
#pragma unroll
                for (int c = 0; c < 4; ++c)
                    acc[r][c] = mfma16(af[r], bfr[c], acc[r][c]);
        }
    }

    if (wsel < 2) {
        bf16* Cb = (wsel == 0) ? Qb : Kb;
#pragma unroll
        for (int c = 0; c < 4; ++c) {
            const int col = n0 + wc + c * 16 + l16;
            const float bvl = (float)bias[col];
#pragma unroll
            for (int r = 0; r < 4; ++r)
#pragma unroll
                for (int v = 0; v < 4; ++v) {
                    const int row = m0 + wr + r * 16 + quad * 4 + v;
                    Cb[(size_t)row * 1024 + col] = (bf16)(acc[r][c][v] + bvl);
                }
        }
    } else {
        __bf16* Ls = smem;   // [128 d][132 stride] = 33.8KB scratch
        __syncthreads();     // all MFMA LDS reads done before overwrite
#pragma unroll
        for (int c = 0; c < 4; ++c) {
            const int col = wc + c * 16 + l16;  // d-local in [0,128)
            const float bvl = (float)bias[n0 + col];
#pragma unroll
            for (int r = 0; r < 4; ++r)
#pragma unroll
                for (int v = 0; v < 4; ++v) {
                    const int row = wr + r * 16 + quad * 4 + v;  // s_local
                    Ls[col * 132 + row] = (__bf16)(acc[r][c][v] + bvl);
                }
        }
        __syncthreads();
        const int b = m0 >> 10, s0 = m0 & 1023, h0 = n0 >> 6;
        const int d = tid >> 1, sg2 = (tid & 1) * 64;    // d in [0,128)
        bf16* g = Vt + ((size_t)((b * NUM_HEADS + h0 + (d >> 6)) * 64 + (d & 63))) * SEQ
                  + s0 + sg2;
#pragma unroll
        for (int c = 0; c < 64; c += 8)
            *(bf16x8*)(void*)(g + c) = *(const bf16x8*)&Ls[d * 132 + sg2 + c];
    }
}

// ---------------------------------------------------------------------------
// Flash attention (r8/r11/r13 structure — best measured 53 us; pinned by the
// barrier-convoy + LDS round-trip chain; r9/r10/r11/r12 probes all bracketed).
// ---------------------------------------------------------------------------
__global__ __launch_bounds__(256, 3) void attn_mfma_kernel(const bf16* __restrict__ Q,
                                                           const bf16* __restrict__ Kc,
                                                           const bf16* __restrict__ Vt,
                                                           const bf16* __restrict__ Er,
                                                           bf16* __restrict__ Opart,
                                                           float* __restrict__ Ml) {
    const int i0 = blockIdx.x * 128;
    const int h = blockIdx.y;
    const int zz = blockIdx.z;
    const int b = zz / 3, jsel = zz - b * 3;
    const int tid = threadIdx.x;
    const int wave = tid >> 6, lane = tid & 63, quad = lane >> 4, l16 = lane & 15;

    const int jbeg = (jsel == 0) ? 0 : ((jsel == 1) ? 384 : 704);
    const int nt   = (jsel == 0) ? 6 : 5;

    __shared__ __bf16 Ks[64][72];
    __shared__ __bf16 Vs[80][72];        // rows 0..63: V^T tile; row 64: ones; 65..79: 0
    __shared__ __bf16 scr_all[4][3264];  // per-wave: T' [96][34] / P [32][72]; Qs alias
    __bf16* scr = &scr_all[wave][0];
    __bf16* Qs = &scr_all[0][0];

    for (int e = tid; e < 16 * 72; e += 256) {
        const int r = e / 72, c = e - r * 72;
        Vs[64 + r][c] = (r == 0) ? (__bf16)1.0f : (__bf16)0.0f;
    }
    {   // stage Q (128 rows x 64) into scr alias
        const int r = tid >> 1, cg = (tid & 1) * 32;
        const bf16* g = Q + ((size_t)(b * SEQ + i0 + r)) * D_MODEL + h * 64 + cg;
#pragma unroll
        for (int c = 0; c < 32; c += 8)
            *(bf16x8*)(void*)(Qs + r * 72 + cg + c) = *(const bf16x8*)(const void*)(g + c);
    }
    __syncthreads();
    bf16x8 aq[2][2];
#pragma unroll
    for (int half = 0; half < 2; ++half)
#pragma unroll
        for (int kk = 0; kk < 2; ++kk)
            aq[half][kk] = *(const bf16x8*)(const void*)(
                Qs + (wave * 32 + half * 16 + l16) * 72 + kk * 32 + quad * 8);

    floatx4 oacc[5][2];   // ct 0..3: O columns; ct 4: row-sum l
#pragma unroll
    for (int ct = 0; ct < 5; ++ct)
#pragma unroll
        for (int half = 0; half < 2; ++half) oacc[ct][half] = (floatx4)0.f;

    const int eb = 960 + i0;
    const bf16* Kg = Kc + (size_t)b * SEQ * D_MODEL + h * 64;
    const bf16* Vtg = Vt + (size_t)((b * NUM_HEADS + h) * 64) * SEQ;

    const int r4 = tid >> 2, c4 = (tid & 3) * 16;
    bf16x8 kp0, kp1, vp0, vp1;
    {   // prefetch first K/V tile
        const bf16* kg = Kg + (size_t)(jbeg + r4) * D_MODEL + c4;
        const bf16* vg = Vtg + (size_t)r4 * SEQ + jbeg + c4;
        kp0 = *(const bf16x8*)(const void*)kg;
        kp1 = *(const bf16x8*)(const void*)(kg + 8);
        vp0 = *(const bf16x8*)(const void*)vg;
        vp1 = *(const bf16x8*)(const void*)(vg + 8);
    }

    for (int t = 0; t < nt; ++t) {
        const int j0 = jbeg + t * 64;
        __syncthreads();  // barrier A: prior tile's Ks/Vs reads done
        *(bf16x8*)&Ks[r4][c4]     = kp0;
        *(bf16x8*)&Ks[r4][c4 + 8] = kp1;
        *(bf16x8*)&Vs[r4][c4]     = vp0;
        *(bf16x8*)&Vs[r4][c4 + 8] = vp1;
        __syncthreads();  // barrier B: tile visible
        if (t < nt - 1) { // prefetch next tile (overlaps compute below)
            const int jn = j0 + 64;
            const bf16* kg = Kg + (size_t)(jn + r4) * D_MODEL + c4;
            const bf16* vg = Vtg + (size_t)r4 * SEQ + jn + c4;
            kp0 = *(const bf16x8*)(const void*)kg;
            kp1 = *(const bf16x8*)(const void*)(kg + 8);
            vp0 = *(const bf16x8*)(const void*)vg;
            vp1 = *(const bf16x8*)(const void*)(vg + 8);
        }

        // BD: Er b-frags from global, MFMA, spill transposed to wave scratch
#pragma unroll
        for (int ct = 0; ct < 6; ++ct) {
            const int erow = eb - j0 + wave * 32 + ct * 16 + l16;
            const bf16* ep = Er + (size_t)erow * 64 + quad * 8;
            bf16x8 be0 = *(const bf16x8*)(const void*)ep;
            bf16x8 be1 = *(const bf16x8*)(const void*)(ep + 32);
#pragma unroll
            for (int half = 0; half < 2; ++half) {
                floatx4 tv = (floatx4)0.f;
                tv = mfma16(aq[half][0], be0, tv);
                tv = mfma16(aq[half][1], be1, tv);
                bf16x4 tb;
#pragma unroll
                for (int v = 0; v < 4; ++v) tb[v] = (__bf16)tv[v];
                *(bf16x4*)(void*)(scr + (ct * 16 + l16) * 34 + half * 16 + quad * 4) = tb;
            }
        }
        // AC = Q.K^T (hides T'-spill latency)
        floatx4 sfrag[4][2];
#pragma unroll
        for (int ct = 0; ct < 4; ++ct) {
            bf16x8 bk0 = *(const bf16x8*)&Ks[ct * 16 + l16][quad * 8];
            bf16x8 bk1 = *(const bf16x8*)&Ks[ct * 16 + l16][32 + quad * 8];
#pragma unroll
            for (int half = 0; half < 2; ++half) {
                floatx4 s = (floatx4)0.f;
                s = mfma16(aq[half][0], bk0, s);
                s = mfma16(aq[half][1], bk1, s);
                sfrag[ct][half] = s;
            }
        }
        // Phase 1: gather ALL BD values (every T' read completes into sfrag)
#pragma unroll
        for (int ct = 0; ct < 4; ++ct)
#pragma unroll
            for (int half = 0; half < 2; ++half)
#pragma unroll
                for (int v = 0; v < 4; ++v) {
                    const int rl = half * 16 + quad * 4 + v;
                    const int cl = 63 + rl - (ct * 16 + l16);
                    sfrag[ct][half][v] =
                        (sfrag[ct][half][v] + (float)scr[cl * 34 + rl]) * 0.125f;
                }
        // Phase 2: P = exp(score) -> scratch (T' dead; no RAW hazard)
#pragma unroll
        for (int ct = 0; ct < 4; ++ct)
#pragma unroll
            for (int half = 0; half < 2; ++half)
#pragma unroll
                for (int v = 0; v < 4; ++v) {
                    const int rl = half * 16 + quad * 4 + v;
                    scr[rl * 72 + ct * 16 + l16] = (__bf16)__expf(sfrag[ct][half][v]);
                }
        // O += P.V ; l += P.1
        bf16x8 ap[2][2];
#pragma unroll
        for (int half = 0; half < 2; ++half)
#pragma unroll
            for (int kk = 0; kk < 2; ++kk)
                ap[half][kk] = *(const bf16x8*)(const void*)(
                    scr + (half * 16 + l16) * 72 + kk * 32 + quad * 8);
#pragma unroll
        for (int ct = 0; ct < 5; ++ct) {
            bf16x8 bv0 = *(const bf16x8*)&Vs[ct * 16 + l16][quad * 8];
            bf16x8 bv1 = *(const bf16x8*)&Vs[ct * 16 + l16][32 + quad * 8];
#pragma unroll
            for (int half = 0; half < 2; ++half) {
                oacc[ct][half] = mfma16(ap[half][0], bv0, oacc[ct][half]);
                oacc[ct][half] = mfma16(ap[half][1], bv1, oacc[ct][half]);
            }
        }
    }

    // epilogue: unnormalized bf16 O-partials + l
    bf16* Op = Opart + (size_t)jsel * 2097152;
#pragma unroll
    for (int ct = 0; ct < 4; ++ct)
#pragma unroll
        for (int half = 0; half < 2; ++half)
#pragma unroll
            for (int v = 0; v < 4; ++v) {
                const int row = i0 + wave * 32 + half * 16 + quad * 4 + v;
                const int col = h * 64 + ct * 16 + l16;
                Op[((size_t)(b * SEQ + row)) * D_MODEL + col] = (bf16)oacc[ct][half][v];
            }
    if (l16 == 0) {
        const int base = ((jsel * 2 + b) * 16 + h) * 1024;
#pragma unroll
        for (int half = 0; half < 2; ++half)
#pragma unroll
            for (int v = 0; v < 4; ++v) {
                const int ig = i0 + wave * 32 + half * 16 + quad * 4 + v;
                Ml[base + ig] = oacc[4][half][v];
            }
    }
}

// ---------------------------------------------------------------------------
// Combine 3 j-split partials: Ob = (O1~+O2~+O3~) / (l1+l2+l3). 8 elems/thr.
// ---------------------------------------------------------------------------
__global__ __launch_bounds__(256) void combine_kernel(const bf16* __restrict__ Opart,
                                                      const float* __restrict__ Ml,
                                                      bf16* __restrict__ Ob) {
    const int e = (blockIdx.x * 256 + threadIdx.x) * 8;
    const int row = e >> 10;
    const int b = row >> 10, i = row & 1023;
    const int h = (e & 1023) >> 6;
    float l = 0.f;
#pragma unroll
    for (int s = 0; s < 3; ++s) l += Ml[(((s * 2 + b) * 16 + h) << 10) + i];
    const float inv = 1.0f / l;
    bf16x8 o1 = *(const bf16x8*)(const void*)(Opart + e);
    bf16x8 o2 = *(const bf16x8*)(const void*)(Opart + 2097152 + e);
    bf16x8 o3 = *(const bf16x8*)(const void*)(Opart + 4194304 + e);
    bf16x8 o;
#pragma unroll
    for (int v = 0; v < 8; ++v)
        o[v] = (__bf16)(((float)o1[v] + (float)o2[v] + (float)o3[v]) * inv);
    *(bf16x8*)(void*)(Ob + e) = o;
}

// ---------------------------------------------------------------------------
// Output GEMM (r13): 64x64 tiles, BK=128, XOR-swizzled DMA staging.
// LDS 32KB; 512 blocks -> 2/CU. Dual-dtype store.
// ---------------------------------------------------------------------------
__global__ __launch_bounds__(256) void gemm_out_kernel(const bf16* __restrict__ A,
        const bf16* __restrict__ W, const bf16* __restrict__ bias,
        void* __restrict__ C, const int* __restrict__ flag) {
    const int n0 = blockIdx.x * 64;
    const int m0 = blockIdx.y * 64;
    __shared__ __bf16 smem[64 * 128 * 2];  // As | Bs, 32KB
    __bf16* As = smem;          // [64][128]
    __bf16* Bs = smem + 8192;   // [64][128]
    const int tid = threadIdx.x;
    const int wave = tid >> 6, lane = tid & 63, quad = lane >> 4, l16 = lane & 15;
    const int wr = (wave >> 1) * 32, wc = (wave & 1) * 32;
    const int lrow = lane >> 4, lcg = lane & 15;

    floatx4 acc[2][2];
#pragma unroll
    for (int r = 0; r < 2; ++r)
#pragma unroll
        for (int c = 0; c < 2; ++c) acc[r][c] = (floatx4)0.f;

    for (int k0 = 0; k0 < 1024; k0 += 128) {
        __syncthreads();
#pragma unroll
        for (int i = 0; i < 4; ++i) {
            const int ci = wave * 4 + i;                 // chunks 0..15
            const int grow = ci * 4 + lrow;              // 0..63
            const int gcg = lcg ^ (grow & 15);
            gl_lds16(A + (size_t)(m0 + grow) * 1024 + k0 + gcg * 8, As + ci * 512);
            gl_lds16(W + (size_t)(n0 + grow) * 1024 + k0 + gcg * 8, Bs + ci * 512);
        }
        __syncthreads();
#pragma unroll
        for (int kk = 0; kk < 4; ++kk) {
            bf16x8 af[2], bfr[2];
            const int sg = ((kk * 4 + quad) ^ l16) * 8;
#pragma unroll
            for (int r = 0; r < 2; ++r)
                af[r] = *(const bf16x8*)&As[(wr + r * 16 + l16) * 128 + sg];
#pragma unroll
            for (int c = 0; c < 2; ++c)
                bfr[c] = *(const bf16x8*)&Bs[(wc + c * 16 + l16) * 128 + sg];
#pragma unroll
            for (int r = 0; r < 2; ++r)
#pragma unroll
                for (int c = 0; c < 2; ++c)
                    acc[r][c] = mfma16(af[r], bfr[c], acc[r][c]);
        }
    }
#pragma unroll
    for (int c = 0; c < 2; ++c) {
        const int col = n0 + wc + c * 16 + l16;
        const float bvl = (float)bias[col];
#pragma unroll
        for (int r = 0; r < 2; ++r)
#pragma unroll
            for (int v = 0; v < 4; ++v) {
                const int row = m0 + wr + r * 16 + quad * 4 + v;
                const float val = acc[r][c][v] + bvl;
                const size_t idx = (size_t)row * 1024 + col;
                if (*flag) ((float*)C)[idx] = val;
                else       ((bf16*)C)[idx] = (bf16)val;
            }
    }
}

// ---------------------------------------------------------------------------
extern "C" void kernel_launch(void* const* d_in, const int* in_sizes, int n_in,
                              void* d_out, int out_size, void* d_ws, size_t ws_size,
                              hipStream_t stream) {
    const size_t E_X = 2097152;       // 2048 x 1024
    const size_t E_CANON = 6426624;

    char* ws = (char*)d_ws;
    int* flag = (int*)ws;
    bf16* canon = (bf16*)(ws + 16);
    bf16* xc  = canon;
    bf16* Wqc = canon + 2097152;
    bf16* Wkc = canon + 3145728;
    bf16* Wvc = canon + 4194304;
    bf16* Woc = canon + 5242880;
    bf16* bqc = canon + 6291456;
    bf16* bkc = canon + 6292480;
    bf16* bvc = canon + 6293504;
    bf16* boc = canon + 6294528;
    bf16* Erc = canon + 6295552;
    bf16* p = canon + E_CANON;
    bf16* Qb    = p;  p += E_X;       // reused as Ob after combine
    bf16* Kb    = p;  p += E_X;
    bf16* Vt    = p;  p += E_X;
    bf16* Opart = p;  p += 3 * E_X;   // bf16 unnormalized partials, 3 j-splits
    float* Ml   = (float*)p;          // [3 jsel][2 b][16 h][1024 i] = 98304 f32

    ConvSrcs cs;
    cs.p[0] = d_in[0]; cs.p[1] = d_in[1]; cs.p[2] = d_in[3]; cs.p[3] = d_in[5];
    cs.p[4] = d_in[7]; cs.p[5] = d_in[2]; cs.p[6] = d_in[4]; cs.p[7] = d_in[6];
    cs.p[8] = d_in[8]; cs.p[9] = d_in[9];
    convert_all_kernel<<<3138, 256, 0, stream>>>(cs, canon, flag);

    gemm_qkv_kernel<<<dim3(24, 16), 256, 0, stream>>>(xc, Wqc, Wkc, Wvc,
                                                      bqc, bkc, bvc, Qb, Kb, Vt);

    attn_mfma_kernel<<<dim3(8, 16, 6), 256, 0, stream>>>(Qb, Kb, Vt, Erc, Opart, Ml);

    combine_kernel<<<1024, 256, 0, stream>>>(Opart, Ml, Qb);  // Ob overlays Qb

    gemm_out_kernel<<<dim3(16, 32), 256, 0, stream>>>(Qb, Woc, boc, d_out, flag);
}